// Round 21
// baseline (223.652 us; speedup 1.0000x reference)
//
#include <hip/hip_runtime.h>
#include <hip/hip_bf16.h>
#include <hip/hip_fp16.h>

#define NN 50000
#define NEDGE 800000
#define INDIM 256
#define NH 8
#define ND 32
#define HD 256
#define NT 4
#define NF 16

typedef __attribute__((ext_vector_type(8))) short s16x8;
typedef __attribute__((ext_vector_type(4))) float f32x4;
typedef unsigned short u16;
typedef unsigned long long u64;

__device__ __forceinline__ float bf2f(u16 u) {
    return __uint_as_float(((unsigned int)u) << 16);
}
__device__ __forceinline__ u16 f2bf(float f) {
    __hip_bfloat16 h = __float2bfloat16(f);
    return *reinterpret_cast<u16*>(&h);
}
__device__ __forceinline__ u16 f2h(float f) {
    __half h = __float2half(f);
    return *reinterpret_cast<u16*>(&h);
}
__device__ __forceinline__ float h2f(u16 u) {
    __half h = *reinterpret_cast<__half*>(&u);
    return __half2float(h);
}

// ---------------- hist + rank + Wt transpose (cnt pre-zeroed by memsetAsync).
// grid = 3125 blocks; first 256 blocks also do the 65536-element Wt transpose.
__global__ void hist_kernel(const float* __restrict__ W, u16* __restrict__ Wt,
                            const int* __restrict__ dst, int* __restrict__ cnt,
                            int* __restrict__ rank, int ne) {
    int idx = blockIdx.x * 256 + threadIdx.x;
    if (idx < 65536) {
        int k = idx >> 8, c = idx & 255;
        Wt[(size_t)c * 256 + k] = f2bf(W[idx]);
    }
    if (idx < ne) rank[idx] = atomicAdd(&cnt[dst[idx]], 1);
}

// ---------------- MFMA GEMM (clean)
__global__ __launch_bounds__(256) void gemm_mfma(
    const float* __restrict__ feat, const u16* __restrict__ Wt,
    u16* __restrict__ fs, int nrows)
{
    const int tid = threadIdx.x;
    __shared__ u16 At[32 * 256];   // 16 KB, swizzled
    const int brow = blockIdx.x * 32;

    #pragma unroll
    for (int it = 0; it < 4; ++it) {
        int fo = it * 2048 + tid * 8;
        int row = fo >> 8, col = fo & 255;
        int grow = brow + row;
        if (grow >= nrows) grow = nrows - 1;
        const float* gp = feat + (size_t)grow * 256 + col;
        float4 x = *reinterpret_cast<const float4*>(gp);
        float4 y = *reinterpret_cast<const float4*>(gp + 4);
        s16x8 v;
        v[0] = (short)f2bf(x.x); v[1] = (short)f2bf(x.y);
        v[2] = (short)f2bf(x.z); v[3] = (short)f2bf(x.w);
        v[4] = (short)f2bf(y.x); v[5] = (short)f2bf(y.y);
        v[6] = (short)f2bf(y.z); v[7] = (short)f2bf(y.w);
        int byte = (col * 2) ^ ((row & 7) << 4);
        *reinterpret_cast<s16x8*>((char*)At + row * 512 + byte) = v;
    }
    __syncthreads();

    const int wave = tid >> 6, lane = tid & 63;
    const int c0 = wave * 64;
    const int rA = lane & 15;
    const int kg = lane >> 4;

    f32x4 acc[2][4] = {};

    for (int k0 = 0; k0 < 256; k0 += 32) {
        const int kk = k0 + kg * 8;
        const int byte = (kk * 2) ^ ((rA & 7) << 4);
        s16x8 a0 = *reinterpret_cast<const s16x8*>((char*)At + rA * 512 + byte);
        s16x8 a1 = *reinterpret_cast<const s16x8*>((char*)At + (16 + rA) * 512 + byte);
        #pragma unroll
        for (int ct = 0; ct < 4; ++ct) {
            s16x8 b = *reinterpret_cast<const s16x8*>(Wt + (size_t)(c0 + ct * 16 + rA) * 256 + kk);
            acc[0][ct] = __builtin_amdgcn_mfma_f32_16x16x32_bf16(a0, b, acc[0][ct], 0, 0, 0);
            acc[1][ct] = __builtin_amdgcn_mfma_f32_16x16x32_bf16(a1, b, acc[1][ct], 0, 0, 0);
        }
    }

    #pragma unroll
    for (int rt = 0; rt < 2; ++rt) {
        #pragma unroll
        for (int r = 0; r < 4; ++r) {
            int row = brow + rt * 16 + kg * 4 + r;
            if (row < nrows) {
                #pragma unroll
                for (int ct = 0; ct < 4; ++ct) {
                    fs[(size_t)row * 256 + c0 + ct * 16 + rA] = f2bf(acc[rt][ct][r]);
                }
            }
        }
    }
}

// ---------------- el/er (f16)
__global__ __launch_bounds__(256) void elr_kernel(
    const u16* __restrict__ fs,
    const float* __restrict__ attn_l, const float* __restrict__ attn_r,
    u16* __restrict__ el, u16* __restrict__ er, int n)
{
    __shared__ float s_al[NH * ND * NT];
    __shared__ float s_ar[NH * ND * NT];
    for (int i = threadIdx.x; i < NH * ND * NT; i += 256) {
        s_al[i] = attn_l[i];
        s_ar[i] = attn_r[i];
    }
    __syncthreads();
    int wv = threadIdx.x >> 6, lane = threadIdx.x & 63;
    int node = blockIdx.x * 4 + wv;
    if (node >= n) return;
    int h = lane >> 3, j0 = (lane & 7) * 4;
    ushort4 u = *reinterpret_cast<const ushort4*>(fs + (size_t)node * HD + lane * 4);
    float f0 = bf2f(u.x), f1 = bf2f(u.y), f2 = bf2f(u.z), f3 = bf2f(u.w);
    const float* al = s_al + h * (ND * NT) + j0 * NT;
    const float* ar = s_ar + h * (ND * NT) + j0 * NT;
    float pl[NT], pr[NT];
    #pragma unroll
    for (int t = 0; t < NT; ++t) {
        pl[t] = f0*al[t] + f1*al[NT + t] + f2*al[2*NT + t] + f3*al[3*NT + t];
        pr[t] = f0*ar[t] + f1*ar[NT + t] + f2*ar[2*NT + t] + f3*ar[3*NT + t];
    }
    #pragma unroll
    for (int d = 1; d < 8; d <<= 1) {
        #pragma unroll
        for (int t = 0; t < NT; ++t) {
            pl[t] += __shfl_xor(pl[t], d);
            pr[t] += __shfl_xor(pr[t], d);
        }
    }
    if ((lane & 7) == 0) {
        ushort4 ol, orr;
        ol.x = f2h(pl[0]); ol.y = f2h(pl[1]); ol.z = f2h(pl[2]); ol.w = f2h(pl[3]);
        orr.x = f2h(pr[0]); orr.y = f2h(pr[1]); orr.z = f2h(pr[2]); orr.w = f2h(pr[3]);
        *reinterpret_cast<ushort4*>(el + (size_t)node * (NH*NT) + h * NT) = ol;
        *reinterpret_cast<ushort4*>(er + (size_t)node * (NH*NT) + h * NT) = orr;
    }
}

// ---------------- CSR scan
__global__ void scan1_kernel(const int* __restrict__ cnt, int* __restrict__ off,
                             int* __restrict__ blksum, int n) {
    __shared__ int sm[256];
    int i = blockIdx.x * 256 + threadIdx.x;
    int v = (i < n) ? cnt[i] : 0;
    sm[threadIdx.x] = v;
    __syncthreads();
    for (int d = 1; d < 256; d <<= 1) {
        int t = (threadIdx.x >= d) ? sm[threadIdx.x - d] : 0;
        __syncthreads();
        sm[threadIdx.x] += t;
        __syncthreads();
    }
    if (i < n) off[i] = sm[threadIdx.x] - v;
    if (threadIdx.x == 255) blksum[blockIdx.x] = sm[255];
}

__global__ void scan2_kernel(int* blksum, int nb) {
    __shared__ int sm[256];
    int v = (threadIdx.x < nb) ? blksum[threadIdx.x] : 0;
    sm[threadIdx.x] = v;
    __syncthreads();
    for (int d = 1; d < 256; d <<= 1) {
        int t = (threadIdx.x >= d) ? sm[threadIdx.x - d] : 0;
        __syncthreads();
        sm[threadIdx.x] += t;
        __syncthreads();
    }
    blksum[threadIdx.x] = sm[threadIdx.x] - v;
}

__global__ void scan3_kernel(int* __restrict__ off, const int* __restrict__ blksum,
                             int n, int ne) {
    int i = blockIdx.x * 256 + threadIdx.x;
    if (i < n) off[i] += blksum[blockIdx.x];
    if (i == 0) off[n] = ne;
}

// ---------------- edge_all, EK=2: each thread handles 2 edges -> 4 independent
// random gather chains in flight (el/er x2) at unchanged occupancy (VGPR ~35).
// 64 edges/block. Slot-ordered 24B record scatter, atomic-free.
__global__ __launch_bounds__(256) void edge_all_kernel(
    const float* __restrict__ e_pro, const float* __restrict__ mask,
    const float* __restrict__ attn_m,
    const int* __restrict__ src, const int* __restrict__ dst,
    const u16* __restrict__ el, const u16* __restrict__ er,
    const int* __restrict__ off, const int* __restrict__ rank,
    u64* __restrict__ rec, int ne)
{
    __shared__ float4 s_am4[NF][NH];   // 2 KB
    const int tid = threadIdx.x;
    const int eb = blockIdx.x * 64;
    const int j = tid & 7;             // head
    const int g = tid >> 3;            // 0..31
    const int e0 = eb + g;
    const int e1 = eb + g + 32;

    // issue ALL gathers for both edges up front
    int s0 = src[e0], d0 = dst[e0];
    int s1 = src[e1], d1 = dst[e1];
    union { uint2 v; u16 u[4]; } lv0, rv0, lv1, rv1;
    lv0.v = *reinterpret_cast<const uint2*>(el + (size_t)s0 * (NH*NT) + j * NT);
    rv0.v = *reinterpret_cast<const uint2*>(er + (size_t)d0 * (NH*NT) + j * NT);
    lv1.v = *reinterpret_cast<const uint2*>(el + (size_t)s1 * (NH*NT) + j * NT);
    rv1.v = *reinterpret_cast<const uint2*>(er + (size_t)d1 * (NH*NT) + j * NT);
    float4 mk0 = *reinterpret_cast<const float4*>(mask + (size_t)e0 * NT);
    float4 mk1 = *reinterpret_cast<const float4*>(mask + (size_t)e1 * NT);
    float2 ep0 = *reinterpret_cast<const float2*>(e_pro + (size_t)e0 * NF + j * 2);
    float2 ep1 = *reinterpret_cast<const float2*>(e_pro + (size_t)e1 * NF + j * 2);
    int slot0 = 0, slot1 = 0;
    if (j == 0) {
        slot0 = off[d0] + rank[e0];
        slot1 = off[d1] + rank[e1];
    }

    if (tid < 128) {                   // h-fast: 16B stride, conflict-free
        int f = tid >> 3, h = tid & 7;
        s_am4[f][h] = *reinterpret_cast<const float4*>(attn_m + (size_t)h * (NF * NT) + f * NT);
    }
    __syncthreads();

    const int gbase = (tid & 63) & 56;
    float em0 = 0.f, em1 = 0.f;
    #pragma unroll
    for (int f = 0; f < NF; ++f) {
        float4 am = s_am4[f][j];
        float amm0 = mk0.x*am.x + mk0.y*am.y + mk0.z*am.z + mk0.w*am.w;
        float amm1 = mk1.x*am.x + mk1.y*am.y + mk1.z*am.z + mk1.w*am.w;
        float ev0 = __shfl((f & 1) ? ep0.y : ep0.x, gbase | (f >> 1));
        float ev1 = __shfl((f & 1) ? ep1.y : ep1.x, gbase | (f >> 1));
        em0 = fmaf(ev0, amm0, em0);
        em1 = fmaf(ev1, amm1, em1);
    }
    float left0  = mk0.x*h2f(lv0.u[0]) + mk0.y*h2f(lv0.u[1]) + mk0.z*h2f(lv0.u[2]) + mk0.w*h2f(lv0.u[3]);
    float right0 = mk0.x*h2f(rv0.u[0]) + mk0.y*h2f(rv0.u[1]) + mk0.z*h2f(rv0.u[2]) + mk0.w*h2f(rv0.u[3]);
    float left1  = mk1.x*h2f(lv1.u[0]) + mk1.y*h2f(lv1.u[1]) + mk1.z*h2f(lv1.u[2]) + mk1.w*h2f(lv1.u[3]);
    float right1 = mk1.x*h2f(rv1.u[0]) + mk1.y*h2f(rv1.u[1]) + mk1.z*h2f(rv1.u[2]) + mk1.w*h2f(rv1.u[3]);

    float v0 = (left0 + right0 + em0) * (1.0f / 3.0f);
    v0 = v0 > 0.f ? v0 : 0.2f * v0;
    float v1 = (left1 + right1 + em1) * (1.0f / 3.0f);
    v1 = v1 > 0.f ? v1 : 0.2f * v1;
    unsigned hv0 = (unsigned)f2h(__expf(v0));
    unsigned hv1 = (unsigned)f2h(__expf(v1));

    // collect 8 head values to lane 0 of each group, for both edges
    unsigned a01 = (__shfl((int)hv0, gbase | 0) & 0xffff) | ((__shfl((int)hv0, gbase | 1) & 0xffff) << 16);
    unsigned a23 = (__shfl((int)hv0, gbase | 2) & 0xffff) | ((__shfl((int)hv0, gbase | 3) & 0xffff) << 16);
    unsigned a45 = (__shfl((int)hv0, gbase | 4) & 0xffff) | ((__shfl((int)hv0, gbase | 5) & 0xffff) << 16);
    unsigned a67 = (__shfl((int)hv0, gbase | 6) & 0xffff) | ((__shfl((int)hv0, gbase | 7) & 0xffff) << 16);
    unsigned b01 = (__shfl((int)hv1, gbase | 0) & 0xffff) | ((__shfl((int)hv1, gbase | 1) & 0xffff) << 16);
    unsigned b23 = (__shfl((int)hv1, gbase | 2) & 0xffff) | ((__shfl((int)hv1, gbase | 3) & 0xffff) << 16);
    unsigned b45 = (__shfl((int)hv1, gbase | 4) & 0xffff) | ((__shfl((int)hv1, gbase | 5) & 0xffff) << 16);
    unsigned b67 = (__shfl((int)hv1, gbase | 6) & 0xffff) | ((__shfl((int)hv1, gbase | 7) & 0xffff) << 16);

    if (j == 0) {
        u64* r0 = rec + (size_t)slot0 * 3;
        r0[0] = (u64)(unsigned)s0 | ((u64)(unsigned)e0 << 32);
        r0[1] = (u64)a01 | ((u64)a23 << 32);
        r0[2] = (u64)a45 | ((u64)a67 << 32);
        u64* r1 = rec + (size_t)slot1 * 3;
        r1[0] = (u64)(unsigned)s1 | ((u64)(unsigned)e1 << 32);
        r1[1] = (u64)b01 | ((u64)b23 << 32);
        r1[2] = (u64)b45 | ((u64)b67 << 32);
    }
}

// ---------------- agg: fully-sequential phase A + batched fs row loads (r20 proven).
__global__ __launch_bounds__(256) void agg_kernel(
    const int* __restrict__ off, const u64* __restrict__ rec,
    const u16* __restrict__ fs, float* __restrict__ out, int n)
{
    int wv = threadIdx.x >> 6, lane = threadIdx.x & 63;
    int node = blockIdx.x * 4 + wv;
    if (node >= n) return;
    int beg = off[node], end = off[node + 1];
    int deg = end - beg;

    int h = lane & 7, sub = lane >> 3;
    float vc[8];
    int sc[8];
    #pragma unroll
    for (int slot = 0; slot < 8; ++slot) {
        int i = beg + slot * 8 + sub;
        float v = 0.f; int sn = 0;
        if (i < end) {
            const char* base = (const char*)rec + (size_t)i * 24;
            sn = *reinterpret_cast<const int*>(base);
            u16 hv = *reinterpret_cast<const u16*>(base + 8 + 2 * h);
            v = h2f(hv);
        }
        vc[slot] = v; sc[slot] = sn;
    }

    int h2 = lane >> 3;
    const int col = lane * 4;
    float a0 = 0.f, a1 = 0.f, a2 = 0.f, a3 = 0.f, sw = 0.f;
    int deg_ = deg < 64 ? deg : 64;
    int nchunk = (deg_ + 7) >> 3;
    #pragma unroll
    for (int c = 0; c < 8; ++c) {
        if (c >= nchunk) break;               // uniform
        float w8 = vc[c];
        int s8 = sc[c];
        float w[8]; int sn[8];
        #pragma unroll
        for (int q = 0; q < 8; ++q) {
            w[q]  = __shfl(w8, q * 8 + h2);
            sn[q] = __shfl(s8, q * 8 + h2);
        }
        ushort4 u[8];
        #pragma unroll
        for (int q = 0; q < 8; ++q)
            u[q] = *reinterpret_cast<const ushort4*>(fs + (size_t)sn[q] * HD + col);
        #pragma unroll
        for (int q = 0; q < 8; ++q) {         // padding: w=0, sn=0 -> no-op
            sw += w[q];
            a0 = fmaf(w[q], bf2f(u[q].x), a0);
            a1 = fmaf(w[q], bf2f(u[q].y), a1);
            a2 = fmaf(w[q], bf2f(u[q].z), a2);
            a3 = fmaf(w[q], bf2f(u[q].w), a3);
        }
    }
    for (int i = beg + 64; i < end; ++i) {    // rare deg>64 tail
        const char* base = (const char*)rec + (size_t)i * 24;
        int sn = *reinterpret_cast<const int*>(base);
        u16 hv = *reinterpret_cast<const u16*>(base + 8 + 2 * h2);
        float w = h2f(hv);
        sw += w;
        ushort4 u = *reinterpret_cast<const ushort4*>(fs + (size_t)sn * HD + col);
        a0 = fmaf(w, bf2f(u.x), a0); a1 = fmaf(w, bf2f(u.y), a1);
        a2 = fmaf(w, bf2f(u.z), a2); a3 = fmaf(w, bf2f(u.w), a3);
    }
    float invS = sw > 0.f ? 1.f / sw : 0.f;
    a0 *= invS; a1 *= invS; a2 *= invS; a3 *= invS;
    *reinterpret_cast<float4*>(&out[(size_t)node * HD + col]) = make_float4(a0, a1, a2, a3);
}

extern "C" void kernel_launch(void* const* d_in, const int* in_sizes, int n_in,
                              void* d_out, int out_size, void* d_ws, size_t ws_size,
                              hipStream_t stream)
{
    const float* feat   = (const float*)d_in[0];
    const float* e_pro  = (const float*)d_in[1];
    const float* mask   = (const float*)d_in[2];
    const float* W_n    = (const float*)d_in[3];
    const float* attn_l = (const float*)d_in[4];
    const float* attn_r = (const float*)d_in[5];
    const float* attn_m = (const float*)d_in[6];
    const int* src      = (const int*)d_in[7];
    const int* dst      = (const int*)d_in[8];
    float* out = (float*)d_out;

    char* ws = (char*)d_ws;
    size_t o = 0;
    auto alloc = [&](size_t bytes) -> void* {
        void* p = (void*)(ws + o);
        o += (bytes + 255) & ~(size_t)255;
        return p;
    };
    u16* fs     = (u16*)alloc((size_t)NN * HD * 2);
    u16* Wt     = (u16*)alloc((size_t)INDIM * HD * 2);
    u16* el     = (u16*)alloc((size_t)NN * NH * NT * 2);
    u16* er     = (u16*)alloc((size_t)NN * NH * NT * 2);
    u64* rec    = (u64*)alloc((size_t)NEDGE * 24);
    int* rank   = (int*)alloc((size_t)NEDGE * 4);
    int* cnt    = (int*)alloc((size_t)NN * 4);
    int* offs   = (int*)alloc((size_t)(NN + 1) * 4);
    int* blksum = (int*)alloc(256 * 4);
    (void)ws_size; (void)in_sizes; (void)n_in; (void)out_size;

    dim3 b256(256);
    hipMemsetAsync(cnt, 0, (size_t)NN * 4, stream);
    hipLaunchKernelGGL(hist_kernel, dim3((NEDGE + 255) / 256), b256, 0, stream,
                       W_n, Wt, dst, cnt, rank, NEDGE);
    hipLaunchKernelGGL(gemm_mfma, dim3((NN + 31) / 32), b256, 0, stream, feat, Wt, fs, NN);
    hipLaunchKernelGGL(elr_kernel, dim3((NN + 3) / 4), b256, 0, stream, fs, attn_l, attn_r, el, er, NN);
    hipLaunchKernelGGL(scan1_kernel, dim3((NN + 255) / 256), b256, 0, stream, cnt, offs, blksum, NN);
    hipLaunchKernelGGL(scan2_kernel, dim3(1), b256, 0, stream, blksum, (NN + 255) / 256);
    hipLaunchKernelGGL(scan3_kernel, dim3((NN + 255) / 256), b256, 0, stream, offs, blksum, NN, NEDGE);
    hipLaunchKernelGGL(edge_all_kernel, dim3(NEDGE / 64), b256, 0, stream,
                       e_pro, mask, attn_m, src, dst, el, er, offs, rank, rec, NEDGE);
    hipLaunchKernelGGL(agg_kernel, dim3((NN + 3) / 4), b256, 0, stream,
                       offs, rec, fs, out, NN);
}

// Round 23
// 221.616 us; speedup vs baseline: 1.0092x; 1.0092x over previous
//
#include <hip/hip_runtime.h>
#include <hip/hip_bf16.h>
#include <hip/hip_fp16.h>

#define NN 50000
#define NEDGE 800000
#define INDIM 256
#define NH 8
#define ND 32
#define HD 256
#define NT 4
#define NF 16

typedef __attribute__((ext_vector_type(8))) short s16x8;
typedef __attribute__((ext_vector_type(4))) float f32x4;
typedef unsigned short u16;
typedef unsigned long long u64;

__device__ __forceinline__ float bf2f(u16 u) {
    return __uint_as_float(((unsigned int)u) << 16);
}
__device__ __forceinline__ u16 f2bf(float f) {
    __hip_bfloat16 h = __float2bfloat16(f);
    return *reinterpret_cast<u16*>(&h);
}
__device__ __forceinline__ u16 f2h(float f) {
    __half h = __float2half(f);
    return *reinterpret_cast<u16*>(&h);
}
__device__ __forceinline__ float h2f(u16 u) {
    __half h = *reinterpret_cast<__half*>(&u);
    return __half2float(h);
}

// ---------------- prep: W transpose->bf16  +  zero cnt
__global__ __launch_bounds__(256) void prep_kernel(const float* __restrict__ W,
                                                   u16* __restrict__ Wt,
                                                   int* __restrict__ cnt)
{
    int idx = blockIdx.x * 256 + threadIdx.x;   // grid = 256 blocks -> 65536
    int k = idx >> 8, c = idx & 255;
    Wt[(size_t)c * 256 + k] = f2bf(W[idx]);
    if (idx < NN) cnt[idx] = 0;
}

// ---------------- hist + rank: rank[e] = within-dst arrival order.
__global__ void hist_kernel(const int* __restrict__ dst, int* __restrict__ cnt,
                            int* __restrict__ rank, int ne) {
    int e = blockIdx.x * 256 + threadIdx.x;
    if (e < ne) rank[e] = atomicAdd(&cnt[dst[e]], 1);
}

// ---------------- MFMA GEMM (clean)
__global__ __launch_bounds__(256) void gemm_mfma(
    const float* __restrict__ feat, const u16* __restrict__ Wt,
    u16* __restrict__ fs, int nrows)
{
    const int tid = threadIdx.x;
    __shared__ u16 At[32 * 256];   // 16 KB, swizzled
    const int brow = blockIdx.x * 32;

    #pragma unroll
    for (int it = 0; it < 4; ++it) {
        int fo = it * 2048 + tid * 8;
        int row = fo >> 8, col = fo & 255;
        int grow = brow + row;
        if (grow >= nrows) grow = nrows - 1;
        const float* gp = feat + (size_t)grow * 256 + col;
        float4 x = *reinterpret_cast<const float4*>(gp);
        float4 y = *reinterpret_cast<const float4*>(gp + 4);
        s16x8 v;
        v[0] = (short)f2bf(x.x); v[1] = (short)f2bf(x.y);
        v[2] = (short)f2bf(x.z); v[3] = (short)f2bf(x.w);
        v[4] = (short)f2bf(y.x); v[5] = (short)f2bf(y.y);
        v[6] = (short)f2bf(y.z); v[7] = (short)f2bf(y.w);
        int byte = (col * 2) ^ ((row & 7) << 4);
        *reinterpret_cast<s16x8*>((char*)At + row * 512 + byte) = v;
    }
    __syncthreads();

    const int wave = tid >> 6, lane = tid & 63;
    const int c0 = wave * 64;
    const int rA = lane & 15;
    const int kg = lane >> 4;

    f32x4 acc[2][4] = {};

    for (int k0 = 0; k0 < 256; k0 += 32) {
        const int kk = k0 + kg * 8;
        const int byte = (kk * 2) ^ ((rA & 7) << 4);
        s16x8 a0 = *reinterpret_cast<const s16x8*>((char*)At + rA * 512 + byte);
        s16x8 a1 = *reinterpret_cast<const s16x8*>((char*)At + (16 + rA) * 512 + byte);
        #pragma unroll
        for (int ct = 0; ct < 4; ++ct) {
            s16x8 b = *reinterpret_cast<const s16x8*>(Wt + (size_t)(c0 + ct * 16 + rA) * 256 + kk);
            acc[0][ct] = __builtin_amdgcn_mfma_f32_16x16x32_bf16(a0, b, acc[0][ct], 0, 0, 0);
            acc[1][ct] = __builtin_amdgcn_mfma_f32_16x16x32_bf16(a1, b, acc[1][ct], 0, 0, 0);
        }
    }

    #pragma unroll
    for (int rt = 0; rt < 2; ++rt) {
        #pragma unroll
        for (int r = 0; r < 4; ++r) {
            int row = brow + rt * 16 + kg * 4 + r;
            if (row < nrows) {
                #pragma unroll
                for (int ct = 0; ct < 4; ++ct) {
                    fs[(size_t)row * 256 + c0 + ct * 16 + rA] = f2bf(acc[rt][ct][r]);
                }
            }
        }
    }
}

// ---------------- el/er (f16)
__global__ __launch_bounds__(256) void elr_kernel(
    const u16* __restrict__ fs,
    const float* __restrict__ attn_l, const float* __restrict__ attn_r,
    u16* __restrict__ el, u16* __restrict__ er, int n)
{
    __shared__ float s_al[NH * ND * NT];
    __shared__ float s_ar[NH * ND * NT];
    for (int i = threadIdx.x; i < NH * ND * NT; i += 256) {
        s_al[i] = attn_l[i];
        s_ar[i] = attn_r[i];
    }
    __syncthreads();
    int wv = threadIdx.x >> 6, lane = threadIdx.x & 63;
    int node = blockIdx.x * 4 + wv;
    if (node >= n) return;
    int h = lane >> 3, j0 = (lane & 7) * 4;
    ushort4 u = *reinterpret_cast<const ushort4*>(fs + (size_t)node * HD + lane * 4);
    float f0 = bf2f(u.x), f1 = bf2f(u.y), f2 = bf2f(u.z), f3 = bf2f(u.w);
    const float* al = s_al + h * (ND * NT) + j0 * NT;
    const float* ar = s_ar + h * (ND * NT) + j0 * NT;
    float pl[NT], pr[NT];
    #pragma unroll
    for (int t = 0; t < NT; ++t) {
        pl[t] = f0*al[t] + f1*al[NT + t] + f2*al[2*NT + t] + f3*al[3*NT + t];
        pr[t] = f0*ar[t] + f1*ar[NT + t] + f2*ar[2*NT + t] + f3*ar[3*NT + t];
    }
    #pragma unroll
    for (int d = 1; d < 8; d <<= 1) {
        #pragma unroll
        for (int t = 0; t < NT; ++t) {
            pl[t] += __shfl_xor(pl[t], d);
            pr[t] += __shfl_xor(pr[t], d);
        }
    }
    if ((lane & 7) == 0) {
        ushort4 ol, orr;
        ol.x = f2h(pl[0]); ol.y = f2h(pl[1]); ol.z = f2h(pl[2]); ol.w = f2h(pl[3]);
        orr.x = f2h(pr[0]); orr.y = f2h(pr[1]); orr.z = f2h(pr[2]); orr.w = f2h(pr[3]);
        *reinterpret_cast<ushort4*>(el + (size_t)node * (NH*NT) + h * NT) = ol;
        *reinterpret_cast<ushort4*>(er + (size_t)node * (NH*NT) + h * NT) = orr;
    }
}

// ---------------- CSR scan
__global__ void scan1_kernel(const int* __restrict__ cnt, int* __restrict__ off,
                             int* __restrict__ blksum, int n) {
    __shared__ int sm[256];
    int i = blockIdx.x * 256 + threadIdx.x;
    int v = (i < n) ? cnt[i] : 0;
    sm[threadIdx.x] = v;
    __syncthreads();
    for (int d = 1; d < 256; d <<= 1) {
        int t = (threadIdx.x >= d) ? sm[threadIdx.x - d] : 0;
        __syncthreads();
        sm[threadIdx.x] += t;
        __syncthreads();
    }
    if (i < n) off[i] = sm[threadIdx.x] - v;
    if (threadIdx.x == 255) blksum[blockIdx.x] = sm[255];
}

__global__ void scan2_kernel(int* blksum, int nb) {
    __shared__ int sm[256];
    int v = (threadIdx.x < nb) ? blksum[threadIdx.x] : 0;
    sm[threadIdx.x] = v;
    __syncthreads();
    for (int d = 1; d < 256; d <<= 1) {
        int t = (threadIdx.x >= d) ? sm[threadIdx.x - d] : 0;
        __syncthreads();
        sm[threadIdx.x] += t;
        __syncthreads();
    }
    blksum[threadIdx.x] = sm[threadIdx.x] - v;
}

__global__ void scan3_kernel(int* __restrict__ off, const int* __restrict__ blksum,
                             int n, int ne) {
    int i = blockIdx.x * 256 + threadIdx.x;
    if (i < n) off[i] += blksum[blockIdx.x];
    if (i == 0) off[n] = ne;
}

// ---------------- edge_all: streaming logits + SLOT-ORDERED 24B record scatter.
// rec[slot] = {u64(src | e<<32), u64(ev0..3 f16), u64(ev4..7 f16)}.
// Lane 0 of each 8-lane group collects the 8 per-head logits via shfl and
// stores 3 u64s (atomic-free: slot = off[d] + rank[e]).
__global__ __launch_bounds__(256) void edge_all_kernel(
    const float* __restrict__ e_pro, const float* __restrict__ mask,
    const float* __restrict__ attn_m,
    const int* __restrict__ src, const int* __restrict__ dst,
    const u16* __restrict__ el, const u16* __restrict__ er,
    const int* __restrict__ off, const int* __restrict__ rank,
    u64* __restrict__ rec, int ne)
{
    __shared__ float4 s_am4[NF][NH];   // 2 KB only
    const int tid = threadIdx.x;
    const int eb = blockIdx.x * 32;
    const int j = tid & 7;             // head
    const int e = eb + (tid >> 3);

    // early gathers + scatter ingredients
    int s = src[e], d = dst[e];
    union { uint2 v; u16 u[4]; } lv, rv;
    lv.v = *reinterpret_cast<const uint2*>(el + (size_t)s * (NH*NT) + j * NT);
    rv.v = *reinterpret_cast<const uint2*>(er + (size_t)d * (NH*NT) + j * NT);
    float4 mk = *reinterpret_cast<const float4*>(mask + (size_t)e * NT);
    float2 myep = *reinterpret_cast<const float2*>(e_pro + (size_t)e * NF + j * 2);
    int slot = 0;
    if (j == 0) slot = off[d] + rank[e];

    if (tid < 128) {                   // h-fast: 16B stride, conflict-free
        int f = tid >> 3, h = tid & 7;
        s_am4[f][h] = *reinterpret_cast<const float4*>(attn_m + (size_t)h * (NF * NT) + f * NT);
    }
    __syncthreads();

    const int gbase = (tid & 63) & 56;
    float pa = myep.x, pb = myep.y;
    float em = 0.f;
    #pragma unroll
    for (int f = 0; f < NF; ++f) {
        float4 am = s_am4[f][j];
        float amm = mk.x*am.x + mk.y*am.y + mk.z*am.z + mk.w*am.w;
        float epv = __shfl((f & 1) ? pb : pa, gbase | (f >> 1));
        em = fmaf(epv, amm, em);
    }
    float left  = mk.x*h2f(lv.u[0]) + mk.y*h2f(lv.u[1]) + mk.z*h2f(lv.u[2]) + mk.w*h2f(lv.u[3]);
    float right = mk.x*h2f(rv.u[0]) + mk.y*h2f(rv.u[1]) + mk.z*h2f(rv.u[2]) + mk.w*h2f(rv.u[3]);

    float v = (left + right + em) * (1.0f / 3.0f);
    v = v > 0.f ? v : 0.2f * v;
    unsigned hv = (unsigned)f2h(__expf(v));   // this lane's head logit exp, f16 bits

    // collect 8 head values into lane 0 of the group (all lanes execute shfls)
    unsigned p01 = (__shfl((int)hv, gbase | 0) & 0xffff) | ((__shfl((int)hv, gbase | 1) & 0xffff) << 16);
    unsigned p23 = (__shfl((int)hv, gbase | 2) & 0xffff) | ((__shfl((int)hv, gbase | 3) & 0xffff) << 16);
    unsigned p45 = (__shfl((int)hv, gbase | 4) & 0xffff) | ((__shfl((int)hv, gbase | 5) & 0xffff) << 16);
    unsigned p67 = (__shfl((int)hv, gbase | 6) & 0xffff) | ((__shfl((int)hv, gbase | 7) & 0xffff) << 16);

    if (j == 0) {
        u64* r = rec + (size_t)slot * 3;
        r[0] = (u64)(unsigned)s | ((u64)(unsigned)e << 32);
        r[1] = (u64)p01 | ((u64)p23 << 32);
        r[2] = (u64)p45 | ((u64)p67 << 32);
    }
}

// ---------------- agg: fully-sequential phase A (src + ev from slot-ordered rec),
// phase B = batched fs row loads.
__global__ __launch_bounds__(256) void agg_kernel(
    const int* __restrict__ off, const u64* __restrict__ rec,
    const u16* __restrict__ fs, float* __restrict__ out, int n)
{
    int wv = threadIdx.x >> 6, lane = threadIdx.x & 63;
    int node = blockIdx.x * 4 + wv;
    if (node >= n) return;
    int beg = off[node], end = off[node + 1];
    int deg = end - beg;

    int h = lane & 7, sub = lane >> 3;
    float vc[8];
    int sc[8];
    #pragma unroll
    for (int slot = 0; slot < 8; ++slot) {
        int i = beg + slot * 8 + sub;
        float v = 0.f; int sn = 0;
        if (i < end) {
            const char* base = (const char*)rec + (size_t)i * 24;
            sn = *reinterpret_cast<const int*>(base);                 // sequential
            u16 hv = *reinterpret_cast<const u16*>(base + 8 + 2 * h); // sequential
            v = h2f(hv);
        }
        vc[slot] = v; sc[slot] = sn;
    }

    int h2 = lane >> 3;
    const int col = lane * 4;
    float a0 = 0.f, a1 = 0.f, a2 = 0.f, a3 = 0.f, sw = 0.f;
    int deg_ = deg < 64 ? deg : 64;
    int nchunk = (deg_ + 7) >> 3;
    #pragma unroll
    for (int c = 0; c < 8; ++c) {
        if (c >= nchunk) break;               // uniform
        float w8 = vc[c];
        int s8 = sc[c];
        float w[8]; int sn[8];
        #pragma unroll
        for (int q = 0; q < 8; ++q) {
            w[q]  = __shfl(w8, q * 8 + h2);
            sn[q] = __shfl(s8, q * 8 + h2);
        }
        ushort4 u[8];
        #pragma unroll
        for (int q = 0; q < 8; ++q)
            u[q] = *reinterpret_cast<const ushort4*>(fs + (size_t)sn[q] * HD + col);
        #pragma unroll
        for (int q = 0; q < 8; ++q) {         // padding: w=0, sn=0 -> no-op
            sw += w[q];
            a0 = fmaf(w[q], bf2f(u[q].x), a0);
            a1 = fmaf(w[q], bf2f(u[q].y), a1);
            a2 = fmaf(w[q], bf2f(u[q].z), a2);
            a3 = fmaf(w[q], bf2f(u[q].w), a3);
        }
    }
    for (int i = beg + 64; i < end; ++i) {    // rare deg>64 tail
        const char* base = (const char*)rec + (size_t)i * 24;
        int sn = *reinterpret_cast<const int*>(base);
        u16 hv = *reinterpret_cast<const u16*>(base + 8 + 2 * h2);
        float w = h2f(hv);
        sw += w;
        ushort4 u = *reinterpret_cast<const ushort4*>(fs + (size_t)sn * HD + col);
        a0 = fmaf(w, bf2f(u.x), a0); a1 = fmaf(w, bf2f(u.y), a1);
        a2 = fmaf(w, bf2f(u.z), a2); a3 = fmaf(w, bf2f(u.w), a3);
    }
    float invS = sw > 0.f ? 1.f / sw : 0.f;
    a0 *= invS; a1 *= invS; a2 *= invS; a3 *= invS;
    *reinterpret_cast<float4*>(&out[(size_t)node * HD + col]) = make_float4(a0, a1, a2, a3);
}

extern "C" void kernel_launch(void* const* d_in, const int* in_sizes, int n_in,
                              void* d_out, int out_size, void* d_ws, size_t ws_size,
                              hipStream_t stream)
{
    const float* feat   = (const float*)d_in[0];
    const float* e_pro  = (const float*)d_in[1];
    const float* mask   = (const float*)d_in[2];
    const float* W_n    = (const float*)d_in[3];
    const float* attn_l = (const float*)d_in[4];
    const float* attn_r = (const float*)d_in[5];
    const float* attn_m = (const float*)d_in[6];
    const int* src      = (const int*)d_in[7];
    const int* dst      = (const int*)d_in[8];
    float* out = (float*)d_out;

    char* ws = (char*)d_ws;
    size_t o = 0;
    auto alloc = [&](size_t bytes) -> void* {
        void* p = (void*)(ws + o);
        o += (bytes + 255) & ~(size_t)255;
        return p;
    };
    u16* fs     = (u16*)alloc((size_t)NN * HD * 2);
    u16* Wt     = (u16*)alloc((size_t)INDIM * HD * 2);
    u16* el     = (u16*)alloc((size_t)NN * NH * NT * 2);
    u16* er     = (u16*)alloc((size_t)NN * NH * NT * 2);
    u64* rec    = (u64*)alloc((size_t)NEDGE * 24);
    int* rank   = (int*)alloc((size_t)NEDGE * 4);
    int* cnt    = (int*)alloc((size_t)NN * 4);
    int* offs   = (int*)alloc((size_t)(NN + 1) * 4);
    int* blksum = (int*)alloc(256 * 4);
    (void)ws_size; (void)in_sizes; (void)n_in; (void)out_size;

    dim3 b256(256);
    hipLaunchKernelGGL(prep_kernel, dim3(256), b256, 0, stream, W_n, Wt, cnt);
    hipLaunchKernelGGL(hist_kernel, dim3((NEDGE + 255) / 256), b256, 0, stream, dst, cnt, rank, NEDGE);
    hipLaunchKernelGGL(gemm_mfma, dim3((NN + 31) / 32), b256, 0, stream, feat, Wt, fs, NN);
    hipLaunchKernelGGL(elr_kernel, dim3((NN + 3) / 4), b256, 0, stream, fs, attn_l, attn_r, el, er, NN);
    hipLaunchKernelGGL(scan1_kernel, dim3((NN + 255) / 256), b256, 0, stream, cnt, offs, blksum, NN);
    hipLaunchKernelGGL(scan2_kernel, dim3(1), b256, 0, stream, blksum, (NN + 255) / 256);
    hipLaunchKernelGGL(scan3_kernel, dim3((NN + 255) / 256), b256, 0, stream, offs, blksum, NN, NEDGE);
    hipLaunchKernelGGL(edge_all_kernel, dim3(NEDGE / 32), b256, 0, stream,
                       e_pro, mask, attn_m, src, dst, el, er, offs, rank, rec, NEDGE);
    hipLaunchKernelGGL(agg_kernel, dim3((NN + 3) / 4), b256, 0, stream,
                       offs, rec, fs, out, NN);
}